// Round 2
// baseline (328.305 us; speedup 1.0000x reference)
//
#include <hip/hip_runtime.h>

// Problem constants
#define Bq 16
#define Cq 512
#define Nq 4096
#define Hq 512

typedef float f32x4 __attribute__((ext_vector_type(4)));

// ---------------------------------------------------------------------------
// K1 (SINGLE pass over x, atomic-free):
// grid = B*16*4 = 1024 blocks: (b, nc = 256-wide n-slice, cq = 128-c quarter).
// Wave w handles c = cq*128 + w + 4k (k=0..31), lane l owns cols 4l..4l+3.
//  - column sums -> LDS cross-wave reduce -> part_xs_n[cq][b][n]
//  - row sums    -> per-lane partial stored to LDS in-loop (1 ds_write_b32/k,
//    conflict-free), then rotated b128 transpose-reduce (no shfl chains).
// ---------------------------------------------------------------------------
__global__ __launch_bounds__(256) void k1_stats(const float* __restrict__ x,
                                                float* __restrict__ part_xs_n,
                                                float* __restrict__ part_xs_c){
  __shared__ float colred[4][256];
  __shared__ float rowp[4][32][64];   // [wave][k][lane] per-lane row partials
  int blk  = blockIdx.x;
  int b    = blk >> 6;
  int nc   = (blk >> 2) & 15;
  int cq   = blk & 3;
  int wave = threadIdx.x >> 6;
  int lane = threadIdx.x & 63;
  int c0   = cq*128 + wave;
  const float* p = x + ((size_t)b*Cq + c0)*Nq + (nc << 8) + (lane << 2);
  float4 acc = {0.f,0.f,0.f,0.f};
  #pragma unroll 8
  for (int k = 0; k < 32; ++k){
    float4 v = *(const float4*)(p + (size_t)(k*4)*Nq);
    acc.x += v.x; acc.y += v.y; acc.z += v.z; acc.w += v.w;
    rowp[wave][k][lane] = (v.x + v.y) + (v.z + v.w);   // ds_write, banks 0..31x2
  }
  *(float4*)&colred[wave][lane << 2] = acc;
  __syncthreads();
  int t = threadIdx.x;
  part_xs_n[((size_t)(cq*Bq) + b)*Nq + (nc << 8) + t] =
      (colred[0][t] + colred[1][t]) + (colred[2][t] + colred[3][t]);
  if (t < 128){
    // row r = t within quarter: c = cq*128 + t; wave = t&3, k = t>>2
    const float4* rp4 = (const float4*)&rowp[t & 3][t >> 2][0];
    float4 sv = {0.f,0.f,0.f,0.f};
    #pragma unroll
    for (int j4 = 0; j4 < 16; ++j4){
      float4 vv = rp4[(j4 + t) & 15];   // rotation: distinct addr per 16-lane group
      sv.x += vv.x; sv.y += vv.y; sv.z += vv.z; sv.w += vv.w;
    }
    part_xs_c[((size_t)(b*16 + nc) << 9) + cq*128 + t] =
        (sv.x + sv.y) + (sv.z + sv.w);
  }
}

// ---------------------------------------------------------------------------
// K1b: xs_n[b,n] = sum_cq part_xs_n ; xs_c[b,c] = sum_nc part_xs_c
// ---------------------------------------------------------------------------
__global__ __launch_bounds__(256) void k1b_red(const float* __restrict__ part_xs_n,
                                               const float* __restrict__ part_xs_c,
                                               float* __restrict__ xs_n,
                                               float* __restrict__ xs_c){
  int blk = blockIdx.x;
  if (blk < 256){
    int i = (blk << 8) + (int)threadIdx.x;          // over B*N
    float acc = 0.f;
    #pragma unroll
    for (int cq=0; cq<4; ++cq) acc += part_xs_n[(size_t)cq*(Bq*Nq) + i];
    xs_n[i] = acc;
  } else {
    int j = ((blk-256) << 8) + (int)threadIdx.x;    // over B*C
    int b = j >> 9, c = j & 511;
    float acc = 0.f;
    #pragma unroll
    for (int nc=0; nc<16; ++nc) acc += part_xs_c[((size_t)(b*16+nc) << 9) + c];
    xs_c[j] = acc;
  }
}

// ---------------------------------------------------------------------------
// K2: s_cf[b,h] = sum_n xs_n[b,n]*w_cf[h,n]   (blocks [0,512))
//     s_sf[b,h] = sum_c xs_c[b,c]*w_sf[h,c]   (blocks [512,1024))
// ---------------------------------------------------------------------------
__global__ __launch_bounds__(256) void k2_s(const float* __restrict__ w_cf,
                                            const float* __restrict__ w_sf,
                                            const float* __restrict__ xs_n,
                                            const float* __restrict__ xs_c,
                                            float* __restrict__ s_cf,
                                            float* __restrict__ s_sf){
  __shared__ float red[4][Bq];
  int blk = blockIdx.x;
  const float* w; const float* src; float* dst; int L;
  if (blk < Hq) { w = w_cf + (size_t)blk*Nq; src = xs_n; dst = s_cf; L = Nq; }
  else          { w = w_sf + (size_t)(blk-Hq)*Cq; src = xs_c; dst = s_sf; L = Cq; }
  int h = blk & (Hq-1);
  int t = threadIdx.x;
  int wave = t >> 6, lane = t & 63;
  float acc[Bq];
  #pragma unroll
  for (int b=0;b<Bq;b++) acc[b]=0.f;
  for (int i0 = t*4; i0 < L; i0 += 1024){
    float4 wv = *(const float4*)(w + i0);
    #pragma unroll
    for (int b=0;b<Bq;b++){
      float4 sv = *(const float4*)(src + (size_t)b*L + i0);
      acc[b] += wv.x*sv.x + wv.y*sv.y + wv.z*sv.z + wv.w*sv.w;
    }
  }
  #pragma unroll
  for (int b=0;b<Bq;b++){
    float v = acc[b];
    #pragma unroll
    for (int off=32; off; off>>=1) v += __shfl_down(v, off, 64);
    if (lane == 0) red[wave][b] = v;
  }
  __syncthreads();
  if (t < Bq)
    dst[(size_t)t*Hq + h] = (red[0][t]+red[1][t])+(red[2][t]+red[3][t]);
}

// ---------------------------------------------------------------------------
// K3: partial products over 64-h chunks, batch-split (2 halves of 8 b) for
// 2x occupancy (288 blocks). part_cg[hc][b][j] ; part_sg[hc][b][j].
// ---------------------------------------------------------------------------
__global__ __launch_bounds__(256) void k3_v(const float* __restrict__ w_cg,
                                            const float* __restrict__ w_sg,
                                            const float* __restrict__ s_cf,
                                            const float* __restrict__ s_sf,
                                            float* __restrict__ part_cg,
                                            float* __restrict__ part_sg){
  __shared__ float sl[8*64];
  int blk = blockIdx.x;
  const float* w; const float* s; float* dst; int L, jc, hc, bh;
  if (blk < 256){ w=w_cg; s=s_cf; dst=part_cg; L=Nq;
    jc = blk >> 4; hc = (blk >> 1) & 7; bh = blk & 1; }
  else { int k = blk - 256; w=w_sg; s=s_sf; dst=part_sg; L=Cq;
    jc = k >> 4; hc = (k >> 1) & 7; bh = k & 1; }
  int h0 = hc*64, b0 = bh*8;
  for (int i = threadIdx.x; i < 8*64; i += 256){
    int bb = i >> 6, hh = i & 63;
    sl[i] = s[(b0+bb)*Hq + h0 + hh];
  }
  __syncthreads();
  int j = (jc<<8) + (int)threadIdx.x;
  float acc[8];
  #pragma unroll
  for (int bb=0;bb<8;bb++) acc[bb]=0.f;
  #pragma unroll 8
  for (int hh=0; hh<64; ++hh){
    float wv = w[(size_t)(h0+hh)*L + j];
    #pragma unroll
    for (int bb=0;bb<8;bb++) acc[bb] += sl[bb*64+hh]*wv;
  }
  #pragma unroll
  for (int bb=0;bb<8;bb++)
    dst[((size_t)hc*Bq + (b0+bb))*L + j] = acc[bb];
}

// ---------------------------------------------------------------------------
// K4 (SINGLE pass over x; k3b reduction INLINED). Same tiling as K1, same
// LDS-transpose row reduce (no shfl chains).
// ---------------------------------------------------------------------------
__global__ __launch_bounds__(256) void k4_comp(const float* __restrict__ x,
                                               const float* __restrict__ part_cg,
                                               const float* __restrict__ part_sg,
                                               float* __restrict__ part_sp,
                                               float* __restrict__ part_ch){
  __shared__ float colred[4][256];
  __shared__ float rowp[4][32][64];
  __shared__ float vs[128];
  int blk  = blockIdx.x;
  int b    = blk >> 6;
  int nc   = (blk >> 2) & 15;
  int cq   = blk & 3;
  int wave = threadIdx.x >> 6;
  int lane = threadIdx.x & 63;
  int t    = threadIdx.x;
  // inline v_sg chunk for this cq: vs[t] = v_sg[b, cq*128+t]
  if (t < 128){
    int c = cq*128 + t;
    float a = 0.f;
    #pragma unroll
    for (int hc=0; hc<8; ++hc) a += part_sg[((size_t)hc*Bq + b)*Cq + c];
    vs[t] = a;
  }
  // inline v_cg slice: 4 floats per lane
  float4 g = {0.f,0.f,0.f,0.f};
  {
    size_t off = (size_t)b*Nq + (nc << 8) + (lane << 2);
    #pragma unroll
    for (int hc=0; hc<8; ++hc){
      float4 pgv = *(const float4*)(part_cg + (size_t)hc*(Bq*Nq) + off);
      g.x += pgv.x; g.y += pgv.y; g.z += pgv.z; g.w += pgv.w;
    }
  }
  __syncthreads();
  int c0 = cq*128 + wave;
  const float* p = x + ((size_t)b*Cq + c0)*Nq + (nc << 8) + (lane << 2);
  float4 acc = {0.f,0.f,0.f,0.f};
  #pragma unroll 8
  for (int k = 0; k < 32; ++k){
    float4 v = *(const float4*)(p + (size_t)(k*4)*Nq);
    float s = vs[wave + k*4];                       // wave-uniform broadcast read
    acc.x += v.x*s; acc.y += v.y*s; acc.z += v.z*s; acc.w += v.w*s;
    rowp[wave][k][lane] = v.x*g.x + v.y*g.y + v.z*g.z + v.w*g.w;
  }
  *(float4*)&colred[wave][lane << 2] = acc;
  __syncthreads();
  part_sp[((size_t)(cq*Bq) + b)*Nq + (nc << 8) + t] =
      (colred[0][t] + colred[1][t]) + (colred[2][t] + colred[3][t]);
  if (t < 128){
    const float4* rp4 = (const float4*)&rowp[t & 3][t >> 2][0];
    float4 sv = {0.f,0.f,0.f,0.f};
    #pragma unroll
    for (int j4 = 0; j4 < 16; ++j4){
      float4 vv = rp4[(j4 + t) & 15];
      sv.x += vv.x; sv.y += vv.y; sv.z += vv.z; sv.w += vv.w;
    }
    part_ch[((size_t)(b*16 + nc) << 9) + cq*128 + t] =
        (sv.x + sv.y) + (sv.z + sv.w);
  }
}

// ---------------------------------------------------------------------------
// K5: inline partial-reduce + softmax. blocks [0,16): channel; [16,32): spatial.
// ---------------------------------------------------------------------------
__global__ __launch_bounds__(256) void k5_softmax(const float* __restrict__ part_ch,
                                                  const float* __restrict__ part_sp,
                                                  float* __restrict__ out){
  __shared__ float buf[Nq];
  __shared__ float lds[4];
  __shared__ float bcast;
  int blk = blockIdx.x;
  int t = threadIdx.x;
  float* dst; int L;
  const size_t OUT0 = (size_t)Bq*Cq*Nq;
  if (blk < Bq){
    int b = blk; L = Cq;
    for (int c = t; c < Cq; c += 256){
      float s = 0.f;
      #pragma unroll
      for (int nc=0; nc<16; ++nc) s += part_ch[((size_t)(b*16+nc) << 9) + c];
      buf[c] = s;
    }
    dst = out + OUT0 + (size_t)b*Cq;
  } else {
    int b = blk - Bq; L = Nq;
    for (int n = t; n < Nq; n += 256){
      float s = 0.f;
      #pragma unroll
      for (int cq=0; cq<4; ++cq) s += part_sp[((size_t)(cq*Bq)+b)*Nq + n];
      buf[n] = s;
    }
    dst = out + OUT0 + (size_t)Bq*Cq + (size_t)b*Nq;
  }
  __syncthreads();
  float m = -3.4e38f;
  for (int i=t;i<L;i+=256) m = fmaxf(m, buf[i]);
  #pragma unroll
  for (int off=32; off; off>>=1) m = fmaxf(m, __shfl_down(m, off, 64));
  if ((t&63)==0) lds[t>>6]=m;
  __syncthreads();
  if (t==0) bcast = fmaxf(fmaxf(lds[0],lds[1]),fmaxf(lds[2],lds[3]));
  __syncthreads();
  m = bcast;
  float ssum=0.f;
  for (int i=t;i<L;i+=256) ssum += __expf(buf[i]-m);
  #pragma unroll
  for (int off=32; off; off>>=1) ssum += __shfl_down(ssum, off, 64);
  __syncthreads();
  if ((t&63)==0) lds[t>>6]=ssum;
  __syncthreads();
  if (t==0) bcast = 1.f/((lds[0]+lds[1])+(lds[2]+lds[3]));
  __syncthreads();
  float inv = bcast;
  for (int i=t;i<L;i+=256) dst[i] = __expf(buf[i]-m)*inv;
}

// ---------------------------------------------------------------------------
// K6: out[b,c,n] = x[b,c,n] * cm[b,c] * sm[b,n]. One row per block (8192),
// 4 float4 per thread; NT stores (native vector type) keep x resident in L3.
// ---------------------------------------------------------------------------
__global__ __launch_bounds__(256) void k6_out(const float* __restrict__ x,
                                              float* __restrict__ out){
  const size_t OUT0 = (size_t)Bq*Cq*Nq;
  const float* cm = out + OUT0;
  const float* sm = out + OUT0 + (size_t)Bq*Cq;
  int blk = blockIdx.x;              // b*512 + c
  int b = blk >> 9;
  size_t rowoff = (size_t)blk * Nq;
  float cmv = cm[blk];
  const float* sp = sm + (size_t)b*Nq;
  int t = threadIdx.x;
  #pragma unroll
  for (int q = 0; q < 4; ++q){
    int n0 = q*1024 + t*4;
    float4 xv = *(const float4*)(x + rowoff + n0);
    float4 sv = *(const float4*)(sp + n0);
    f32x4 o;
    o.x = xv.x*cmv*sv.x; o.y = xv.y*cmv*sv.y;
    o.z = xv.z*cmv*sv.z; o.w = xv.w*cmv*sv.w;
    __builtin_nontemporal_store(o, (f32x4*)(out + rowoff + n0));
  }
}

extern "C" void kernel_launch(void* const* d_in, const int* in_sizes, int n_in,
                              void* d_out, int out_size, void* d_ws, size_t ws_size,
                              hipStream_t stream){
  const float* x    = (const float*)d_in[0];
  const float* w_cf = (const float*)d_in[1];
  const float* w_cg = (const float*)d_in[2];
  const float* w_sf = (const float*)d_in[3];
  const float* w_sg = (const float*)d_in[4];
  float* out = (float*)d_out;

  float* ws = (float*)d_ws;
  // persistent small buffers
  float* xs_n = ws;                  // B*N   = 65536
  float* xs_c = xs_n + Bq*Nq;        // B*C   = 8192
  float* s_cf = xs_c + Bq*Cq;        // B*H   = 8192
  float* s_sf = s_cf + Bq*Hq;        // B*H   = 8192
  // two disjoint arenas so k3's partials survive into k4 while k4 writes its own:
  float* arenaA = s_sf + Bq*Hq;                 // 589824 floats
  float* part_xs_n = arenaA;                    // 4*B*N  = 262144 (k1 -> k1b)
  float* part_xs_c = arenaA + 4*Bq*Nq;          // 16*B*C = 131072 (k1 -> k1b)
  float* part_cg   = arenaA;                    // 8*B*N  = 524288 (k3 -> k4)
  float* part_sg   = arenaA + 8*Bq*Nq;          // 8*B*C  = 65536  (k3 -> k4)
  float* arenaB = arenaA + 8*Bq*Nq + 8*Bq*Cq;   // 393216 floats
  float* part_sp   = arenaB;                    // 4*B*N  = 262144 (k4 -> k5)
  float* part_ch   = arenaB + 4*Bq*Nq;          // 16*B*C = 131072 (k4 -> k5)
  // total ws: ~4.5 MB; no atomics; no memset (every cell stored before read).

  k1_stats  <<<1024,  256, 0, stream>>>(x, part_xs_n, part_xs_c);
  k1b_red   <<<288,   256, 0, stream>>>(part_xs_n, part_xs_c, xs_n, xs_c);
  k2_s      <<<2*Hq,  256, 0, stream>>>(w_cf, w_sf, xs_n, xs_c, s_cf, s_sf);
  k3_v      <<<288,   256, 0, stream>>>(w_cg, w_sg, s_cf, s_sf, part_cg, part_sg);
  k4_comp   <<<1024,  256, 0, stream>>>(x, part_cg, part_sg, part_sp, part_ch);
  k5_softmax<<<2*Bq,  256, 0, stream>>>(part_ch, part_sp, out);
  k6_out    <<<Bq*Cq, 256, 0, stream>>>(x, out);
}